// Round 2
// baseline (356.295 us; speedup 1.0000x reference)
//
#include <hip/hip_runtime.h>

// B=64, H=W=512, K=7, VALID conv -> 506x506.
#define HW   512
#define OW   506
#define KS   7
#define TW   64     // output tile width  (cols)
#define TH   64     // output tile height (rows)
#define IW   70     // input halo tile 70x70, stored LINEAR (unpadded)
#define NZ   4      // images per block (z-pipelined)
#define NST  10     // staging float2 per thread: ceil(70*70/2/256)=10

__global__ __launch_bounds__(256) void conv7x7_v2(
    const float* __restrict__ in,      // [64][512][512]
    const float* __restrict__ weight,  // [7][7]
    const float* __restrict__ bias,    // [1]
    float* __restrict__ out)           // [64][506][506]
{
    __shared__ float tile[IW * IW];    // 19.6 KB, linear

    const int tid = threadIdx.x;
    const int x0  = blockIdx.x * TW;
    const int y0  = blockIdx.y * TH;
    const int z0  = blockIdx.z * NZ;

    // ---- weights + bias -> SGPRs (uniform) ----
    float wv[KS * KS];
#pragma unroll
    for (int i = 0; i < KS * KS; ++i)
        wv[i] = __uint_as_float(__builtin_amdgcn_readfirstlane(__float_as_uint(weight[i])));
    const float bv = __uint_as_float(__builtin_amdgcn_readfirstlane(__float_as_uint(bias[0])));

    // thread -> (column, row-group) mapping: wave lanes = 64 consecutive cols
    const int c     = tid & 63;        // tile-local output column
    const int g     = tid >> 6;        // row group 0..3 (16 rows each)
    const int cb    = c & ~1;          // 8B-aligned window base
    const bool odd  = (c & 1) != 0;
    const int rbase = 16 * g;

    // ---- precompute staging global offsets (float2 units); -1 = skip ----
    int goff[NST];
#pragma unroll
    for (int k = 0; k < NST; ++k) {
        const int p  = tid + k * 256;
        const int r  = p / 35;                 // magic-mul div
        const int cc = 2 * (p - r * 35);
        const bool ok = (p < (IW * IW / 2)) && (y0 + r < HW) && (x0 + cc < HW);
        goff[k] = ok ? ((y0 + r) * HW + x0 + cc) : -1;
    }

    // ---- stage first image (reg -> LDS, linear so writes are stride-1) ----
    const float* inb0 = in + (size_t)z0 * (HW * HW);
    float2 pf[NST];
#pragma unroll
    for (int k = 0; k < NST; ++k) {
        pf[k] = make_float2(0.f, 0.f);
        if (goff[k] >= 0) pf[k] = *reinterpret_cast<const float2*>(inb0 + goff[k]);
    }
#pragma unroll
    for (int k = 0; k < NST; ++k) {
        const int p = tid + k * 256;
        if (p < (IW * IW / 2)) *reinterpret_cast<float2*>(tile + 2 * p) = pf[k];
    }
    __syncthreads();

    const int ox = x0 + c;

    for (int zi = 0; zi < NZ; ++zi) {
        // ---- T14 issue-early: prefetch next image into registers ----
        const bool havenext = (zi + 1 < NZ);
        const float* inbn = in + (size_t)(z0 + zi + 1) * (HW * HW);
#pragma unroll
        for (int k = 0; k < NST; ++k) {
            pf[k] = make_float2(0.f, 0.f);
            if (havenext && goff[k] >= 0)
                pf[k] = *reinterpret_cast<const float2*>(inbn + goff[k]);
        }

        // ---- sliding 7x7 register window, rotation renamed by full unroll ----
        float w7[7][7];
#pragma unroll
        for (int rr = 0; rr < 6; ++rr) {       // preload rows rbase..rbase+5
            const float* rp = tile + (rbase + rr) * IW + cb;
            const float2 a0 = *reinterpret_cast<const float2*>(rp + 0);
            const float2 a1 = *reinterpret_cast<const float2*>(rp + 2);
            const float2 a2 = *reinterpret_cast<const float2*>(rp + 4);
            const float2 a3 = *reinterpret_cast<const float2*>(rp + 6);
            const float f8[8] = {a0.x, a0.y, a1.x, a1.y, a2.x, a2.y, a3.x, a3.y};
#pragma unroll
            for (int k = 0; k < 7; ++k) w7[rr][k] = odd ? f8[k + 1] : f8[k];
        }

        float* outb = out + (size_t)(z0 + zi) * (OW * OW);

#pragma unroll
        for (int s = 0; s < 16; ++s) {
            {   // load row rbase+s+6 into slot (s+6)%7
                const float* rp = tile + (rbase + s + 6) * IW + cb;
                const float2 a0 = *reinterpret_cast<const float2*>(rp + 0);
                const float2 a1 = *reinterpret_cast<const float2*>(rp + 2);
                const float2 a2 = *reinterpret_cast<const float2*>(rp + 4);
                const float2 a3 = *reinterpret_cast<const float2*>(rp + 6);
                const float f8[8] = {a0.x, a0.y, a1.x, a1.y, a2.x, a2.y, a3.x, a3.y};
                const int sl = (s + 6) % 7;
#pragma unroll
                for (int k = 0; k < 7; ++k) w7[sl][k] = odd ? f8[k + 1] : f8[k];
            }
            // 49 FMAs, 4 partial accumulators to break the dependence chain
            float acc0 = 0.f, acc1 = 0.f, acc2 = 0.f, acc3 = 0.f;
#pragma unroll
            for (int kr = 0; kr < 7; ++kr) {
                const int sl = (s + kr) % 7;   // compile-time after unroll
#pragma unroll
                for (int kc = 0; kc < 7; ++kc) {
                    const float v  = w7[sl][kc];
                    const float wk = wv[kr * 7 + kc];
                    const int a = (kr * 7 + kc) & 3;
                    if      (a == 0) acc0 = fmaf(wk, v, acc0);
                    else if (a == 1) acc1 = fmaf(wk, v, acc1);
                    else if (a == 2) acc2 = fmaf(wk, v, acc2);
                    else             acc3 = fmaf(wk, v, acc3);
                }
            }
            const int oy = y0 + rbase + s;
            if (oy < OW && ox < OW)
                outb[(size_t)oy * OW + ox] = (acc0 + acc1) + (acc2 + acc3) + bv;
        }

        // ---- write prefetched image into LDS for next z iteration ----
        __syncthreads();                        // all waves done reading tile
        if (havenext) {
#pragma unroll
            for (int k = 0; k < NST; ++k) {
                const int p = tid + k * 256;
                if (p < (IW * IW / 2)) *reinterpret_cast<float2*>(tile + 2 * p) = pf[k];
            }
            __syncthreads();
        }
    }
}

extern "C" void kernel_launch(void* const* d_in, const int* in_sizes, int n_in,
                              void* d_out, int out_size, void* d_ws, size_t ws_size,
                              hipStream_t stream) {
    const float* enc_x  = (const float*)d_in[0];
    const float* weight = (const float*)d_in[1];
    const float* bias   = (const float*)d_in[2];
    float* outp         = (float*)d_out;

    dim3 grid(8, 8, 64 / NZ);   // 8x8 tiles of 64x64 over 506x506; 16 z-blocks x NZ images
    dim3 block(256);
    hipLaunchKernelGGL(conv7x7_v2, grid, block, 0, stream,
                       enc_x, weight, bias, outp);
}